// Round 4
// baseline (4410.249 us; speedup 1.0000x reference)
//
#include <hip/hip_runtime.h>
#include <hip/hip_bf16.h>
#include <cmath>

typedef __attribute__((ext_vector_type(8))) short short8;   // 8 bf16 = 4 VGPRs
typedef __attribute__((ext_vector_type(4))) float floatx4;  // MFMA 16x16 accumulator

#define TS   512
#define DIM  1024
#define HD   1024
#define KTOT 2048
#define GRID_BLOCKS 256
#define XSTRIDE 1032                  // LDS row stride (bf16): 2064B (proven 2-way layout)
#define ROWSTRIDE ((size_t)TS * HD)   // batch-row stride of x and out (elements)

// ---------------------------------------------------------------------------
// One-time transpose + fp32->bf16: WT[j][k] = bf16( k<1024 ? Wx[k][j] : Wh[k-1024][j] )
// ---------------------------------------------------------------------------
__global__ void build_wt(const float* __restrict__ Wx,
                         const float* __restrict__ Wh,
                         __hip_bfloat16* __restrict__ WT) {
    __shared__ __hip_bfloat16 tile[32][33];
    const int j0 = blockIdx.x * 32;
    const int k0 = blockIdx.y * 32;
    const int tx = threadIdx.x & 31;
    const int ty = threadIdx.x >> 5;
    #pragma unroll
    for (int kk = 0; kk < 32; kk += 8) {
        const int k = k0 + ty + kk;
        const float* S = (k < DIM) ? (Wx + (size_t)k * 4096)
                                   : (Wh + (size_t)(k - DIM) * 4096);
        tile[ty + kk][tx] = __float2bfloat16(S[j0 + tx]);
    }
    __syncthreads();
    #pragma unroll
    for (int kk = 0; kk < 32; kk += 8) {
        const int j = j0 + ty + kk;
        WT[(size_t)j * KTOT + k0 + tx] = tile[tx][ty + kk];
    }
}

// fast sigmoid/tanh: v_exp_f32 + v_rcp_f32 (~1e-6 rel err, << bf16 noise)
__device__ __forceinline__ float fast_sig(float x) {
    return __builtin_amdgcn_rcpf(1.0f + __expf(-x));
}
__device__ __forceinline__ float fast_tanh(float x) {
    // tanh(x) = 1 - 2/(e^{2x}+1); handles +-inf overflow correctly
    return 1.0f - 2.0f * __builtin_amdgcn_rcpf(1.0f + __expf(2.0f * x));
}

// ---------------------------------------------------------------------------
// Persistent LSTM scan — tagged self-sync + chunked arrival pipeline.
//
// hbuf32[parity][n*1024+j] = (bf16(h)<<16) | tag, tag = t+1. Producer: one
// relaxed agent store, fire & forget. Consumer: polls the words themselves.
//
// Per-step schedule:
//   (A) issue x_{t+1} float4 loads             [in flight whole iteration]
//   (B) x-half MFMA from XB[par]               [hidden under tag flight time]
//   (C) 4-chunk h pipeline: poll c0 / bar / {issue c+1, MFMA c, check c+1,
//       extract, bar} -> post-last-arrival tail is ~1 chunk of MFMA
//   S2, fast-math gates, publish h (tag t+2)
//   (D) convert & park x_{t+1} -> XB[nxt], S3  [hidden in tag flight shadow]
//
// Poll ownership (per chunk, all 256 threads): s=tid&31 -> 8-col slice,
// rows r1=tid>>5 and r1+8. 8 u64 per thread per chunk.
//
// Overwrite safety: producer writes tag t+2 into a parity slot only after its
// own iter-t polls saw tag t+1 from every group member, which happens only
// after every reader's loads of tag t on that slot completed. Monotone ->
// no deadlock. hbuf memset each launch kills stale tags.
// ---------------------------------------------------------------------------
__global__ __launch_bounds__(256, 1)
void lstm_scan(const float* __restrict__ x,
               const float* __restrict__ h0,
               const __hip_bfloat16* __restrict__ WT,
               const float* __restrict__ bias,
               float* __restrict__ out,
               unsigned* __restrict__ hbuf32) {   // 2 * 65536 tagged words
    __shared__ __hip_bfloat16 XB[2][16][XSTRIDE];  // x_t, double-buffered
    __shared__ __hip_bfloat16 Bh[16][XSTRIDE];     // h_{t-1}
    __shared__ float lds_g[4][16][17];             // [gate][j_local][n_local]

    const int blk  = blockIdx.x;
    const int ng   = (blk >> 1) & 3;                    // XCD-pair group
    const int cs   = ((blk >> 3) << 1) | (blk & 1);     // 0..63 within group
    const int tid  = threadIdx.x;
    const int wave = tid >> 6;
    const int lane = tid & 63;
    const int n0 = ng * 16;
    const int j0 = cs * 16;

    const int frag_m = lane & 15;        // A: m (gate-col) / B: n (batch row)
    const int frag_k = (lane >> 4) * 8;  // k sub-offset within 32-chunk

    // ---- publish h0 ASAP (tag 1, parity 0), grid-flat coalesced ----
    const int flat = blk * 256 + tid;    // 0..65535 == n*1024+j
    {
        const unsigned w0 =
            ((unsigned)(unsigned short)__bfloat16_as_short(__float2bfloat16(h0[flat])) << 16) | 1u;
        __hip_atomic_store(hbuf32 + flat, w0,
                           __ATOMIC_RELAXED, __HIP_MEMORY_SCOPE_AGENT);
    }

    // ---- preload this wave's A fragments: 64 x short8 ----
    const __hip_bfloat16* wrow =
        WT + (size_t)(wave * HD + j0 + frag_m) * KTOT + frag_k;
    short8 wreg[64];
    #pragma unroll
    for (int i = 0; i < 32; ++i)
        wreg[i] = *(const short8*)(wrow + i * 32);
    #pragma unroll
    for (int i = 0; i < 32; ++i)
        wreg[32 + i] = *(const short8*)(wrow + DIM + i * 32);

    // ---- stage x_0 -> XB[0] ----
    #pragma unroll
    for (int j = 0; j < 8; ++j) {
        const int c = j * 256 + tid;
        const int r = c >> 7;
        const int col = (c & 127) * 8;
        const float* xs = x + (size_t)(n0 + r) * ROWSTRIDE + col;
        float4 f0 = *(const float4*)xs;
        float4 f1 = *(const float4*)(xs + 4);
        short8 v;
        v[0] = __bfloat16_as_short(__float2bfloat16(f0.x));
        v[1] = __bfloat16_as_short(__float2bfloat16(f0.y));
        v[2] = __bfloat16_as_short(__float2bfloat16(f0.z));
        v[3] = __bfloat16_as_short(__float2bfloat16(f0.w));
        v[4] = __bfloat16_as_short(__float2bfloat16(f1.x));
        v[5] = __bfloat16_as_short(__float2bfloat16(f1.y));
        v[6] = __bfloat16_as_short(__float2bfloat16(f1.z));
        v[7] = __bfloat16_as_short(__float2bfloat16(f1.w));
        *(short8*)&XB[0][r][col] = v;
    }
    __syncthreads();   // S0: XB[0] staged before first (B)

    // ---- epilogue mapping ----
    const int e_j = tid & 15;
    const int e_n = tid >> 4;
    float c_reg = 0.0f;
    const float bi  = bias[         j0 + e_j];
    const float bf_ = bias[1 * HD + j0 + e_j];
    const float bo  = bias[2 * HD + j0 + e_j];
    const float bg  = bias[3 * HD + j0 + e_j];
    float* out_e = out + (size_t)(n0 + e_n) * ROWSTRIDE + j0 + e_j;
    const int hb_idx = (n0 + e_n) * 1024 + j0 + e_j;
    const int q = lane >> 4;

    // poll-ownership constants
    const int s_sl = tid & 31;    // 8-col slice within chunk
    const int r1   = tid >> 5;    // rows r1 and r1+8

    for (int t = 0; t < TS; ++t) {
        const int par = t & 1;
        const int nxt = (t + 1) & 1;

        // ---- (A) issue x_{t+1} loads; in flight the whole iteration ----
        float4 xf[16];
        if (t + 1 < TS) {
            #pragma unroll
            for (int j = 0; j < 8; ++j) {
                const int c = j * 256 + tid;
                const int r = c >> 7;
                const int col = (c & 127) * 8;
                const float* xs = x + (size_t)(n0 + r) * ROWSTRIDE
                                    + (size_t)(t + 1) * DIM + col;
                xf[2 * j]     = *(const float4*)xs;
                xf[2 * j + 1] = *(const float4*)(xs + 4);
            }
        }

        // ---- (B) x-half MFMA (no h dependency; hides tag flight time) ----
        floatx4 a0 = {0.f, 0.f, 0.f, 0.f};
        floatx4 a1 = {0.f, 0.f, 0.f, 0.f};
        #pragma unroll
        for (int i = 0; i < 32; i += 2) {
            short8 b8a = *(const short8*)&XB[par][frag_m][i * 32 + frag_k];
            short8 b8b = *(const short8*)&XB[par][frag_m][(i + 1) * 32 + frag_k];
            a0 = __builtin_amdgcn_mfma_f32_16x16x32_bf16(wreg[i],     b8a, a0, 0, 0, 0);
            a1 = __builtin_amdgcn_mfma_f32_16x16x32_bf16(wreg[i + 1], b8b, a1, 0, 0, 0);
        }

        // ---- (C) chunked h pipeline ----
        const unsigned long long* pb =
            (const unsigned long long*)hbuf32 + ((size_t)par << 15);
        const unsigned long long tagpat =
            (unsigned long long)(unsigned)(t + 1)
            | ((unsigned long long)(unsigned)(t + 1) << 32);
        unsigned long long hb[8];
        floatx4 a2 = {0.f, 0.f, 0.f, 0.f};
        floatx4 a3 = {0.f, 0.f, 0.f, 0.f};

#define ISSUE8(CC) do {                                                        \
        const size_t o1 = ((size_t)(n0 + r1) << 9) + ((CC) << 7) + (s_sl << 2);\
        _Pragma("unroll")                                                      \
        for (int qq = 0; qq < 4; ++qq)                                         \
            hb[qq] = __hip_atomic_load(pb + o1 + qq,                           \
                __ATOMIC_RELAXED, __HIP_MEMORY_SCOPE_AGENT);                   \
        _Pragma("unroll")                                                      \
        for (int qq = 0; qq < 4; ++qq)                                         \
            hb[4 + qq] = __hip_atomic_load(pb + o1 + (8 << 9) + qq,            \
                __ATOMIC_RELAXED, __HIP_MEMORY_SCOPE_AGENT);                   \
    } while (0)

#define TAGOK() ({ bool ok_ = true;                                            \
        _Pragma("unroll")                                                      \
        for (int kk = 0; kk < 8; ++kk)                                         \
            ok_ = ok_ && ((hb[kk] & 0x0000FFFF0000FFFFull) == tagpat);         \
        ok_; })

#define SPIN(CC) do { ISSUE8(CC); } while (!__all((int)TAGOK()))

#define CHECKSPIN(CC) do { if (!__all((int)TAGOK())) { SPIN(CC); } } while (0)

#define EXTRACT(CC) do {                                                       \
        const int cb = (CC) * 256 + s_sl * 8;                                  \
        short8 v0, v1;                                                         \
        _Pragma("unroll")                                                      \
        for (int qq = 0; qq < 4; ++qq) {                                       \
            const unsigned long long u = hb[qq];                               \
            v0[2 * qq]     = (short)(unsigned short)(u >> 16);                 \
            v0[2 * qq + 1] = (short)(unsigned short)(u >> 48);                 \
            const unsigned long long w = hb[4 + qq];                           \
            v1[2 * qq]     = (short)(unsigned short)(w >> 16);                 \
            v1[2 * qq + 1] = (short)(unsigned short)(w >> 48);                 \
        }                                                                      \
        *(short8*)&Bh[r1][cb]     = v0;                                        \
        *(short8*)&Bh[r1 + 8][cb] = v1;                                        \
    } while (0)

#define HMFMA(CC) do {                                                         \
        _Pragma("unroll")                                                      \
        for (int k = 0; k < 8; k += 2) {                                       \
            short8 b8a = *(const short8*)&Bh[frag_m][((CC)*8 + k)     * 32 + frag_k]; \
            short8 b8b = *(const short8*)&Bh[frag_m][((CC)*8 + k + 1) * 32 + frag_k]; \
            a2 = __builtin_amdgcn_mfma_f32_16x16x32_bf16(wreg[32 + (CC)*8 + k],     b8a, a2, 0, 0, 0); \
            a3 = __builtin_amdgcn_mfma_f32_16x16x32_bf16(wreg[32 + (CC)*8 + k + 1], b8b, a3, 0, 0, 0); \
        }                                                                      \
    } while (0)

        SPIN(0); EXTRACT(0);
        __syncthreads();                 // C0 staged
        ISSUE8(1); HMFMA(0); CHECKSPIN(1); EXTRACT(1);
        __syncthreads();                 // C1 staged
        ISSUE8(2); HMFMA(1); CHECKSPIN(2); EXTRACT(2);
        __syncthreads();                 // C2 staged
        ISSUE8(3); HMFMA(2); CHECKSPIN(3); EXTRACT(3);
        __syncthreads();                 // C3 staged
        HMFMA(3);

        floatx4 acc = (a0 + a1) + (a2 + a3);

        // ---- gate tile -> lds_g ----
        #pragma unroll
        for (int r = 0; r < 4; ++r)
            lds_g[wave][q * 4 + r][frag_m] = acc[r];
        __syncthreads();   // S2

        // ---- gates + state update (fast math; right before publish) ----
        const float ai = lds_g[0][e_j][e_n] + bi;
        const float af = lds_g[1][e_j][e_n] + bf_;
        const float ao = lds_g[2][e_j][e_n] + bo;
        const float ag = lds_g[3][e_j][e_n] + bg;
        const float i_g = fast_sig(ai);
        const float f_g = fast_sig(af);
        const float o_g = fast_sig(ao);
        const float g_g = fast_tanh(ag);
        c_reg = f_g * c_reg + i_g * g_g;
        const float h = o_g * fast_tanh(c_reg);

        // ---- publish tagged h: ONE fire-and-forget store, ASAP ----
        if (t + 1 < TS) {
            const unsigned wrd =
                ((unsigned)(unsigned short)__bfloat16_as_short(__float2bfloat16(h)) << 16)
                | (unsigned)(t + 2);
            __hip_atomic_store(hbuf32 + (((size_t)nxt) << 16) + hb_idx, wrd,
                               __ATOMIC_RELAXED, __HIP_MEMORY_SCOPE_AGENT);
        }

        // fp32 output — fire-and-forget
        out_e[(size_t)t * HD] = h;

        // ---- (D) convert & park x_{t+1} (hidden in tag flight shadow) ----
        if (t + 1 < TS) {
            #pragma unroll
            for (int j = 0; j < 8; ++j) {
                const int c = j * 256 + tid;
                const int r = c >> 7;
                const int col = (c & 127) * 8;
                const float4 f0 = xf[2 * j];
                const float4 f1 = xf[2 * j + 1];
                short8 v;
                v[0] = __bfloat16_as_short(__float2bfloat16(f0.x));
                v[1] = __bfloat16_as_short(__float2bfloat16(f0.y));
                v[2] = __bfloat16_as_short(__float2bfloat16(f0.z));
                v[3] = __bfloat16_as_short(__float2bfloat16(f0.w));
                v[4] = __bfloat16_as_short(__float2bfloat16(f1.x));
                v[5] = __bfloat16_as_short(__float2bfloat16(f1.y));
                v[6] = __bfloat16_as_short(__float2bfloat16(f1.z));
                v[7] = __bfloat16_as_short(__float2bfloat16(f1.w));
                *(short8*)&XB[nxt][r][col] = v;
            }
            __syncthreads();   // S3: XB[nxt] ready for next iter's (B)
        }
    }
#undef ISSUE8
#undef TAGOK
#undef SPIN
#undef CHECKSPIN
#undef EXTRACT
#undef HMFMA
}

// ---------------------------------------------------------------------------
extern "C" void kernel_launch(void* const* d_in, const int* in_sizes, int n_in,
                              void* d_out, int out_size, void* d_ws, size_t ws_size,
                              hipStream_t stream) {
    const float* x  = (const float*)d_in[0];
    const float* h0 = (const float*)d_in[1];
    const float* Wx = (const float*)d_in[2];
    const float* Wh = (const float*)d_in[3];
    const float* b  = (const float*)d_in[4];
    float* out = (float*)d_out;

    char* ws = (char*)d_ws;
    __hip_bfloat16* WT     = (__hip_bfloat16*)ws;              // 16 MiB
    unsigned*       hbuf32 = (unsigned*)(ws + (16u << 20));    // 512 KiB (2 x 65536 x 4B)

    hipMemsetAsync(hbuf32, 0, 2 * 65536 * sizeof(unsigned), stream);  // kill stale tags
    build_wt<<<dim3(128, 64), 256, 0, stream>>>(Wx, Wh, WT);
    lstm_scan<<<GRID_BLOCKS, 256, 0, stream>>>(x, h0, WT, b, out, hbuf32);
}

// Round 5
// 3330.074 us; speedup vs baseline: 1.3244x; 1.3244x over previous
//
#include <hip/hip_runtime.h>
#include <hip/hip_bf16.h>
#include <cmath>

typedef __attribute__((ext_vector_type(8))) short short8;   // 8 bf16 = 4 VGPRs
typedef __attribute__((ext_vector_type(4))) float floatx4;  // MFMA 16x16 accumulator

#define TS   512
#define DIM  1024
#define HD   1024
#define KTOT 2048
#define GRID_BLOCKS 256
#define RING 4                        // h ring depth (must be >=2; 4 gives L2-eviction distance)
#define XSTRIDE 1032                  // LDS row stride (bf16): 2064B (proven 2-way layout)
#define ROWSTRIDE ((size_t)TS * HD)   // batch-row stride of x and out (elements)

// ---------------------------------------------------------------------------
// One-time transpose + fp32->bf16: WT[j][k] = bf16( k<1024 ? Wx[k][j] : Wh[k-1024][j] )
// ---------------------------------------------------------------------------
__global__ void build_wt(const float* __restrict__ Wx,
                         const float* __restrict__ Wh,
                         __hip_bfloat16* __restrict__ WT) {
    __shared__ __hip_bfloat16 tile[32][33];
    const int j0 = blockIdx.x * 32;
    const int k0 = blockIdx.y * 32;
    const int tx = threadIdx.x & 31;
    const int ty = threadIdx.x >> 5;
    #pragma unroll
    for (int kk = 0; kk < 32; kk += 8) {
        const int k = k0 + ty + kk;
        const float* S = (k < DIM) ? (Wx + (size_t)k * 4096)
                                   : (Wh + (size_t)(k - DIM) * 4096);
        tile[ty + kk][tx] = __float2bfloat16(S[j0 + tx]);
    }
    __syncthreads();
    #pragma unroll
    for (int kk = 0; kk < 32; kk += 8) {
        const int j = j0 + ty + kk;
        WT[(size_t)j * KTOT + k0 + tx] = tile[tx][ty + kk];
    }
}

// fast sigmoid/tanh: v_exp_f32 + v_rcp_f32 (~1e-6 rel err, << bf16 noise)
__device__ __forceinline__ float fast_sig(float x) {
    return __builtin_amdgcn_rcpf(1.0f + __expf(-x));
}
__device__ __forceinline__ float fast_tanh(float x) {
    return 1.0f - 2.0f * __builtin_amdgcn_rcpf(1.0f + __expf(2.0f * x));
}

// ---------------------------------------------------------------------------
// Persistent LSTM scan — tagged self-sync, canary-gated L2-cached bulk read.
//
// hbuf32[slot][n*1024+j] = (bf16(h)<<16) | tag; h_t lives in slot t%RING with
// tag t+1. Producer: one relaxed agent-scope store (write-through to LLC),
// fire & forget. Consumer protocol per step:
//   1) CANARY: spin (agent-scope) on 64 tiny words, one per producer
//      (256B/block/round instead of 64KB/round -> no LLC bandwidth storm).
//   2) BULK: read the 16x1024 h-slice ONCE with normal CACHED loads (L2 can
//      serve same-XCD peers; ring depth 4 makes reused slots ~evicted so the
//      refill comes fresh from LLC).
//   3) VERIFY: per-word tag check; stale words (rare: surviving stale L2
//      line or partial-arrival) are re-read agent-scope until fresh.
// Correctness never depends on L2 behavior: tags validate every word, and
// the fallback path is the round-3-proven agent-scope read.
//
// Overwrite safety (RING>=2): publishing tag t+2 into slot (t+1)%RING
// happens only after this block's iter-t poll saw tag t+1 from all peers,
// which transitively implies every reader finished its reads of the slot's
// previous contents (tag t+2-RING). Exact-match tag compare is safe: a
// writer can be at most 2 iters ahead, so slot t%RING never carries a
// future tag while this block is at iter t. hbuf memset each launch.
// ---------------------------------------------------------------------------
__global__ __launch_bounds__(256, 1)
void lstm_scan(const float* __restrict__ x,
               const float* __restrict__ h0,
               const __hip_bfloat16* __restrict__ WT,
               const float* __restrict__ bias,
               float* __restrict__ out,
               unsigned* __restrict__ hbuf32) {   // RING * 65536 tagged words
    __shared__ __hip_bfloat16 XB[2][16][XSTRIDE];  // x_t, double-buffered
    __shared__ __hip_bfloat16 Bh[16][XSTRIDE];     // h_{t-1}
    __shared__ float lds_g[4][16][17];             // [gate][j_local][n_local]

    const int blk  = blockIdx.x;
    const int ng   = (blk >> 1) & 3;                    // XCD-pair group
    const int cs   = ((blk >> 3) << 1) | (blk & 1);     // 0..63 within group
    const int tid  = threadIdx.x;
    const int wave = tid >> 6;
    const int lane = tid & 63;
    const int n0 = ng * 16;
    const int j0 = cs * 16;

    const int frag_m = lane & 15;        // A: m (gate-col) / B: n (batch row)
    const int frag_k = (lane >> 4) * 8;  // k sub-offset within 32-chunk

    // ---- publish h0 ASAP (tag 1, slot 0), grid-flat coalesced ----
    const int flat = blk * 256 + tid;    // 0..65535 == n*1024+j
    {
        const unsigned w0 =
            ((unsigned)(unsigned short)__bfloat16_as_short(__float2bfloat16(h0[flat])) << 16) | 1u;
        __hip_atomic_store(hbuf32 + flat, w0,
                           __ATOMIC_RELAXED, __HIP_MEMORY_SCOPE_AGENT);
    }

    // ---- preload this wave's A fragments: 64 x short8 ----
    const __hip_bfloat16* wrow =
        WT + (size_t)(wave * HD + j0 + frag_m) * KTOT + frag_k;
    short8 wreg[64];
    #pragma unroll
    for (int i = 0; i < 32; ++i)
        wreg[i] = *(const short8*)(wrow + i * 32);
    #pragma unroll
    for (int i = 0; i < 32; ++i)
        wreg[32 + i] = *(const short8*)(wrow + DIM + i * 32);

    // ---- stage x_0 -> XB[0] ----
    #pragma unroll
    for (int j = 0; j < 8; ++j) {
        const int c = j * 256 + tid;
        const int r = c >> 7;
        const int col = (c & 127) * 8;
        const float* xs = x + (size_t)(n0 + r) * ROWSTRIDE + col;
        float4 f0 = *(const float4*)xs;
        float4 f1 = *(const float4*)(xs + 4);
        short8 v;
        v[0] = __bfloat16_as_short(__float2bfloat16(f0.x));
        v[1] = __bfloat16_as_short(__float2bfloat16(f0.y));
        v[2] = __bfloat16_as_short(__float2bfloat16(f0.z));
        v[3] = __bfloat16_as_short(__float2bfloat16(f0.w));
        v[4] = __bfloat16_as_short(__float2bfloat16(f1.x));
        v[5] = __bfloat16_as_short(__float2bfloat16(f1.y));
        v[6] = __bfloat16_as_short(__float2bfloat16(f1.z));
        v[7] = __bfloat16_as_short(__float2bfloat16(f1.w));
        *(short8*)&XB[0][r][col] = v;
    }

    // ---- epilogue mapping ----
    const int e_j = tid & 15;
    const int e_n = tid >> 4;
    float c_reg = 0.0f;
    const float bi  = bias[         j0 + e_j];
    const float bf_ = bias[1 * HD + j0 + e_j];
    const float bo  = bias[2 * HD + j0 + e_j];
    const float bg  = bias[3 * HD + j0 + e_j];
    float* out_e = out + (size_t)(n0 + e_n) * ROWSTRIDE + j0 + e_j;
    const int hb_idx = (n0 + e_n) * 1024 + j0 + e_j;
    const int q = lane >> 4;

    // canary word for producer `lane`: one word inside that producer's
    // 16x16 tile (row n0+(lane&15), col 16*lane+(lane>>4)) -> 64 distinct lines
    const unsigned c_idx =
        (unsigned)((n0 + (lane & 15)) * 1024 + lane * 16 + (lane >> 4));

    for (int t = 0; t < TS; ++t) {
        const int slot_r = t & (RING - 1);
        const int slot_w = (t + 1) & (RING - 1);

        // ---- (A) issue x_{t+1} loads; in flight during poll ----
        float4 xf[16];
        if (t + 1 < TS) {
            #pragma unroll
            for (int j = 0; j < 8; ++j) {
                const int c = j * 256 + tid;
                const int r = c >> 7;
                const int col = (c & 127) * 8;
                const float* xs = x + (size_t)(n0 + r) * ROWSTRIDE
                                    + (size_t)(t + 1) * DIM + col;
                xf[2 * j]     = *(const float4*)xs;
                xf[2 * j + 1] = *(const float4*)(xs + 4);
            }
        }

        const unsigned* pb32 = hbuf32 + ((size_t)slot_r << 16);
        const unsigned tg = (unsigned)(t + 1);

        // ---- (B1) canary spin: 64 x 4B agent-scope, all waves ----
        for (;;) {
            unsigned v = __hip_atomic_load(pb32 + c_idx,
                __ATOMIC_RELAXED, __HIP_MEMORY_SCOPE_AGENT);
            if (__all((int)((v & 0xFFFFu) == tg))) break;
            __builtin_amdgcn_s_sleep(1);
        }
        asm volatile("" ::: "memory");   // don't hoist cached bulk above spin

        // ---- (B2) bulk h read: ONE cached pass (L2-served for peers) ----
        const unsigned long long* pb = (const unsigned long long*)pb32;
        const unsigned long long tagpat =
            (unsigned long long)tg | ((unsigned long long)tg << 32);
        unsigned long long hb[32];
        #pragma unroll
        for (int j = 0; j < 8; ++j) {
            const int c = j * 256 + tid;
            const int r = c >> 7;
            const int col = (c & 127) * 8;
            const size_t o = (size_t)(((n0 + r) << 10) + col) >> 1;
            #pragma unroll
            for (int qq = 0; qq < 4; ++qq)
                hb[4 * j + qq] = pb[o + qq];
        }

        // ---- (B3) verify tags; agent-scope re-read of stale words ----
        for (;;) {
            bool ok = true;
            #pragma unroll
            for (int k = 0; k < 32; ++k)
                ok = ok && ((hb[k] & 0x0000FFFF0000FFFFull) == tagpat);
            if (__all((int)ok)) break;
            #pragma unroll
            for (int j = 0; j < 8; ++j) {
                const int c = j * 256 + tid;
                const int r = c >> 7;
                const int col = (c & 127) * 8;
                const size_t o = (size_t)(((n0 + r) << 10) + col) >> 1;
                #pragma unroll
                for (int qq = 0; qq < 4; ++qq)
                    if ((hb[4 * j + qq] & 0x0000FFFF0000FFFFull) != tagpat)
                        hb[4 * j + qq] = __hip_atomic_load(pb + o + qq,
                            __ATOMIC_RELAXED, __HIP_MEMORY_SCOPE_AGENT);
            }
        }

        // ---- (C) extract bf16 (high halves) -> Bh ----
        #pragma unroll
        for (int j = 0; j < 8; ++j) {
            const int c = j * 256 + tid;
            const int r = c >> 7;
            const int col = (c & 127) * 8;
            short8 v;
            #pragma unroll
            for (int qq = 0; qq < 4; ++qq) {
                const unsigned long long u = hb[4 * j + qq];
                v[2 * qq]     = (short)(unsigned short)(u >> 16);
                v[2 * qq + 1] = (short)(unsigned short)(u >> 48);
            }
            *(short8*)&Bh[r][col] = v;
        }

        // ---- (D) convert & park x_{t+1} -> XB[(t+1)&1] ----
        if (t + 1 < TS) {
            #pragma unroll
            for (int j = 0; j < 8; ++j) {
                const int c = j * 256 + tid;
                const int r = c >> 7;
                const int col = (c & 127) * 8;
                const float4 f0 = xf[2 * j];
                const float4 f1 = xf[2 * j + 1];
                short8 v;
                v[0] = __bfloat16_as_short(__float2bfloat16(f0.x));
                v[1] = __bfloat16_as_short(__float2bfloat16(f0.y));
                v[2] = __bfloat16_as_short(__float2bfloat16(f0.z));
                v[3] = __bfloat16_as_short(__float2bfloat16(f0.w));
                v[4] = __bfloat16_as_short(__float2bfloat16(f1.x));
                v[5] = __bfloat16_as_short(__float2bfloat16(f1.y));
                v[6] = __bfloat16_as_short(__float2bfloat16(f1.z));
                v[7] = __bfloat16_as_short(__float2bfloat16(f1.w));
                *(short8*)&XB[(t + 1) & 1][r][col] = v;
            }
        }
        __syncthreads();   // S1: Bh + XB[(t+1)&1] staged; XB[par] stable

        // ---- MFMA: A from regs, B from LDS; 4 independent acc chains ----
        const int par = t & 1;
        floatx4 a0 = {0.f, 0.f, 0.f, 0.f};
        floatx4 a1 = {0.f, 0.f, 0.f, 0.f};
        floatx4 a2 = {0.f, 0.f, 0.f, 0.f};
        floatx4 a3 = {0.f, 0.f, 0.f, 0.f};
        #pragma unroll
        for (int i = 0; i < 32; i += 2) {
            short8 b8a = *(const short8*)&XB[par][frag_m][i * 32 + frag_k];
            short8 b8b = *(const short8*)&XB[par][frag_m][(i + 1) * 32 + frag_k];
            a0 = __builtin_amdgcn_mfma_f32_16x16x32_bf16(wreg[i],     b8a, a0, 0, 0, 0);
            a1 = __builtin_amdgcn_mfma_f32_16x16x32_bf16(wreg[i + 1], b8b, a1, 0, 0, 0);
        }
        #pragma unroll
        for (int i = 0; i < 32; i += 2) {
            short8 b8a = *(const short8*)&Bh[frag_m][i * 32 + frag_k];
            short8 b8b = *(const short8*)&Bh[frag_m][(i + 1) * 32 + frag_k];
            a2 = __builtin_amdgcn_mfma_f32_16x16x32_bf16(wreg[32 + i], b8a, a2, 0, 0, 0);
            a3 = __builtin_amdgcn_mfma_f32_16x16x32_bf16(wreg[33 + i], b8b, a3, 0, 0, 0);
        }
        floatx4 acc = (a0 + a1) + (a2 + a3);

        // ---- gate tile -> lds_g ----
        #pragma unroll
        for (int r = 0; r < 4; ++r)
            lds_g[wave][q * 4 + r][frag_m] = acc[r];
        __syncthreads();   // S2

        // ---- gates + state update (fast math; right before publish) ----
        const float ai = lds_g[0][e_j][e_n] + bi;
        const float af = lds_g[1][e_j][e_n] + bf_;
        const float ao = lds_g[2][e_j][e_n] + bo;
        const float ag = lds_g[3][e_j][e_n] + bg;
        const float i_g = fast_sig(ai);
        const float f_g = fast_sig(af);
        const float o_g = fast_sig(ao);
        const float g_g = fast_tanh(ag);
        c_reg = f_g * c_reg + i_g * g_g;
        const float h = o_g * fast_tanh(c_reg);

        // ---- publish tagged h: ONE fire-and-forget store, ASAP ----
        if (t + 1 < TS) {
            const unsigned wrd =
                ((unsigned)(unsigned short)__bfloat16_as_short(__float2bfloat16(h)) << 16)
                | (unsigned)(t + 2);
            __hip_atomic_store(hbuf32 + (((size_t)slot_w) << 16) + hb_idx, wrd,
                               __ATOMIC_RELAXED, __HIP_MEMORY_SCOPE_AGENT);
        }

        // fp32 output — fire-and-forget
        out_e[(size_t)t * HD] = h;
    }
}

// ---------------------------------------------------------------------------
extern "C" void kernel_launch(void* const* d_in, const int* in_sizes, int n_in,
                              void* d_out, int out_size, void* d_ws, size_t ws_size,
                              hipStream_t stream) {
    const float* x  = (const float*)d_in[0];
    const float* h0 = (const float*)d_in[1];
    const float* Wx = (const float*)d_in[2];
    const float* Wh = (const float*)d_in[3];
    const float* b  = (const float*)d_in[4];
    float* out = (float*)d_out;

    char* ws = (char*)d_ws;
    __hip_bfloat16* WT     = (__hip_bfloat16*)ws;              // 16 MiB
    unsigned*       hbuf32 = (unsigned*)(ws + (16u << 20));    // 1 MiB (RING x 65536 x 4B)

    hipMemsetAsync(hbuf32, 0, RING * 65536 * sizeof(unsigned), stream);  // kill stale tags
    build_wt<<<dim3(128, 64), 256, 0, stream>>>(Wx, Wh, WT);
    lstm_scan<<<GRID_BLOCKS, 256, 0, stream>>>(x, h0, WT, b, out, hbuf32);
}